// Round 1
// baseline (168.259 us; speedup 1.0000x reference)
//
#include <hip/hip_runtime.h>
#include <float.h>

// Problem constants (B=64, S=16, N=256, T=256, D=500, NUM_FRAMES=16, TOPK=3)
static constexpr long OUT0 = 0;          // props_feats  (1024, 16, 500)  = 8,192,000
static constexpr long OUT1 = 8192000;    // overlaps     (64,16,256,256)  = 67,108,864
static constexpr long OUT2 = 75300864;   // max_timestamps (64,16,3,2)    = 6,144
static constexpr long OUT3 = 75307008;   // max_scores   (64,16,3)        = 3,072

// ---------------------------------------------------------------------------
// Kernel A: props_feats gather. One block per (b,s); 2000 float4 per block.
// ---------------------------------------------------------------------------
__global__ __launch_bounds__(256) void propfeat_kernel(
    const float* __restrict__ frames, const float* __restrict__ props,
    const float* __restrict__ duration, float* __restrict__ out) {
  int bs = blockIdx.x;            // 0..1023 = b*16+s
  int b = bs >> 4;
  float dur = duration[b];
  float p0 = props[bs * 2 + 0];
  float p1 = props[bs * 2 + 1];
  // s_fr = min(int(p0/dur*T), T-1); truncation toward zero matches astype(int32)
  int s_fr = (int)(p0 / dur * 256.0f); if (s_fr > 255) s_fr = 255;
  int e_fr = (int)(p1 / dur * 256.0f); if (e_fr > 255) e_fr = 255;
  bool zp = (p0 == 0.0f) && (p1 == 0.0f) && (dur == 0.0f);
  float sf = (float)s_fr;
  float df = (float)(e_fr - s_fr);
  const float4* f4 = (const float4*)frames + (long)b * (256L * 125L);
  float4* o4 = (float4*)out + OUT0 / 4 + (long)bs * (16L * 125L);
  // 16 frames x 125 float4 each = 2000 float4 per (b,s)
  for (int k = threadIdx.x; k < 2000; k += 256) {
    int f = k / 125;            // frame step 0..15 (const-div -> magic mul)
    int w = k - f * 125;        // float4 within row
    // lin = s_fr + (step*diff)/16 ; both factors integral -> exact in f32
    float lin = sf + ((float)f * df) * (1.0f / 16.0f);
    int idx = (int)lin; if (idx > 255) idx = 255; if (idx < 0) idx = 0;
    float4 v = f4[(long)idx * 125 + w];
    if (zp) { v.x = 0.0f; v.y = 0.0f; v.z = 0.0f; v.w = 0.0f; }
    o4[k] = v;
  }
}

// ---------------------------------------------------------------------------
// Kernel B: fused overlaps write + top-3 (+sum) over scores. One block/(b,s).
// ---------------------------------------------------------------------------
__device__ __forceinline__ void insert3(float v, int id, float tv[3], int ti[3]) {
  // total order: larger value first; tie -> smaller index first (lax.top_k)
  if (v > tv[0] || (v == tv[0] && id < ti[0])) {
    tv[2] = tv[1]; ti[2] = ti[1];
    tv[1] = tv[0]; ti[1] = ti[0];
    tv[0] = v;     ti[0] = id;
  } else if (v > tv[1] || (v == tv[1] && id < ti[1])) {
    tv[2] = tv[1]; ti[2] = ti[1];
    tv[1] = v;     ti[1] = id;
  } else if (v > tv[2] || (v == tv[2] && id < ti[2])) {
    tv[2] = v;     ti[2] = id;
  }
}

__global__ __launch_bounds__(256) void ov_topk_kernel(
    const float* __restrict__ scores, const float* __restrict__ yt,
    const float* __restrict__ duration, float* __restrict__ out) {
  __shared__ float sv[768];
  __shared__ int   si[768];
  __shared__ float ssum[256];

  int bs = blockIdx.x;      // b*16+s
  int b = bs >> 4;
  int tid = threadIdx.x;
  float dur = duration[b];
  float gs = yt[bs * 2 + 0];
  float ge = yt[bs * 2 + 1];
  bool gz = (gs == 0.0f) && (ge == 0.0f);
  const float inv256 = 1.0f / 256.0f;   // exact pow2: x*inv256 == x/256

  const float4* s4 = (const float4*)scores + (long)bs * 16384L;
  float4* o4 = (float4*)out + OUT1 / 4 + (long)bs * 16384L;

  float tv[3] = {-FLT_MAX, -FLT_MAX, -FLT_MAX};
  int   ti[3] = {0x7fffffff, 0x7fffffff, 0x7fffffff};
  float lsum = 0.0f;

  for (int it = 0; it < 64; ++it) {
    int k = it * 256 + tid;       // float4 index within the 256x256 map
    float4 sc = s4[k];
    int i = k >> 6;               // row (proposal start bin)
    int j = (k & 63) << 2;        // col base (end bin), 4 per float4
    float ps = (float)i * dur * inv256;
    float4 ov;
    {
      float pe = (float)(j + 1) * dur * inv256;
      float in_ = fmaxf(0.0f, fminf(pe, ge) - fmaxf(ps, gs));
      float un  = fmaxf(0.0f, fmaxf(pe, ge) - fminf(ps, gs));
      ov.x = gz ? 0.0f : in_ / (un + 1e-6f);
    }
    {
      float pe = (float)(j + 2) * dur * inv256;
      float in_ = fmaxf(0.0f, fminf(pe, ge) - fmaxf(ps, gs));
      float un  = fmaxf(0.0f, fmaxf(pe, ge) - fminf(ps, gs));
      ov.y = gz ? 0.0f : in_ / (un + 1e-6f);
    }
    {
      float pe = (float)(j + 3) * dur * inv256;
      float in_ = fmaxf(0.0f, fminf(pe, ge) - fmaxf(ps, gs));
      float un  = fmaxf(0.0f, fmaxf(pe, ge) - fminf(ps, gs));
      ov.z = gz ? 0.0f : in_ / (un + 1e-6f);
    }
    {
      float pe = (float)(j + 4) * dur * inv256;
      float in_ = fmaxf(0.0f, fminf(pe, ge) - fmaxf(ps, gs));
      float un  = fmaxf(0.0f, fmaxf(pe, ge) - fminf(ps, gs));
      ov.w = gz ? 0.0f : in_ / (un + 1e-6f);
    }
    o4[k] = ov;

    int fidx = k << 2;            // flat index into N*N
    insert3(sc.x, fidx + 0, tv, ti);
    insert3(sc.y, fidx + 1, tv, ti);
    insert3(sc.z, fidx + 2, tv, ti);
    insert3(sc.w, fidx + 3, tv, ti);
    lsum += sc.x + sc.y + sc.z + sc.w;
  }

  ssum[tid] = lsum;
  sv[tid * 3 + 0] = tv[0]; si[tid * 3 + 0] = ti[0];
  sv[tid * 3 + 1] = tv[1]; si[tid * 3 + 1] = ti[1];
  sv[tid * 3 + 2] = tv[2]; si[tid * 3 + 2] = ti[2];
  __syncthreads();

  // block sum reduce (value only needs to clear the 0.001 threshold; ~32768)
  for (int sft = 128; sft > 0; sft >>= 1) {
    if (tid < sft) ssum[tid] += ssum[tid + sft];
    __syncthreads();
  }

  // stage 1: 256 -> 64 candidate lists (thread t merges t, t+64, t+128, t+192)
  if (tid < 64) {
    float fv[3] = {-FLT_MAX, -FLT_MAX, -FLT_MAX};
    int   fi[3] = {0x7fffffff, 0x7fffffff, 0x7fffffff};
    for (int t = tid; t < 256; t += 64) {
      insert3(sv[t * 3 + 0], si[t * 3 + 0], fv, fi);
      insert3(sv[t * 3 + 1], si[t * 3 + 1], fv, fi);
      insert3(sv[t * 3 + 2], si[t * 3 + 2], fv, fi);
    }
    sv[tid * 3 + 0] = fv[0]; si[tid * 3 + 0] = fi[0];
    sv[tid * 3 + 1] = fv[1]; si[tid * 3 + 1] = fi[1];
    sv[tid * 3 + 2] = fv[2]; si[tid * 3 + 2] = fi[2];
  }
  __syncthreads();

  // stage 2: thread 0 merges 64 lists (192 candidates), writes outputs 2 & 3
  if (tid == 0) {
    float fv[3] = {-FLT_MAX, -FLT_MAX, -FLT_MAX};
    int   fi[3] = {0x7fffffff, 0x7fffffff, 0x7fffffff};
    for (int t = 0; t < 64; ++t) {
      insert3(sv[t * 3 + 0], si[t * 3 + 0], fv, fi);
      insert3(sv[t * 3 + 1], si[t * 3 + 1], fv, fi);
      insert3(sv[t * 3 + 2], si[t * 3 + 2], fv, fi);
    }
    float total = ssum[0];
    bool valid = total > 0.001f;
    float* o2 = out + OUT2 + (long)bs * 6;
    float* o3 = out + OUT3 + (long)bs * 3;
    for (int r = 0; r < 3; ++r) {
      float pi = (float)(fi[r] >> 8);     // top_idx // N
      float pj = (float)(fi[r] & 255);    // top_idx % N
      o3[r]         = valid ? fv[r] : 0.0f;
      o2[r * 2 + 0] = valid ? (pi * inv256) * dur : 0.0f;   // (pos/N)*duration
      o2[r * 2 + 1] = valid ? (pj * inv256) * dur : 0.0f;
    }
  }
}

extern "C" void kernel_launch(void* const* d_in, const int* in_sizes, int n_in,
                              void* d_out, int out_size, void* d_ws, size_t ws_size,
                              hipStream_t stream) {
  const float* frames   = (const float*)d_in[0];  // (64,256,500)
  const float* props    = (const float*)d_in[1];  // (64,16,2)
  const float* duration = (const float*)d_in[2];  // (64,)
  const float* yt       = (const float*)d_in[3];  // (64,16,1,2)
  const float* scores   = (const float*)d_in[4];  // (64,16,1,256,256)
  float* out = (float*)d_out;

  hipLaunchKernelGGL(propfeat_kernel, dim3(1024), dim3(256), 0, stream,
                     frames, props, duration, out);
  hipLaunchKernelGGL(ov_topk_kernel, dim3(1024), dim3(256), 0, stream,
                     scores, yt, duration, out);
}

// Round 2
// 149.363 us; speedup vs baseline: 1.1265x; 1.1265x over previous
//
#include <hip/hip_runtime.h>
#include <float.h>

// Problem constants (B=64, S=16, N=256, T=256, D=500, NUM_FRAMES=16, TOPK=3)
static constexpr long OUT0 = 0;          // props_feats  (1024, 16, 500)  = 8,192,000
static constexpr long OUT1 = 8192000;    // overlaps     (64,16,256,256)  = 67,108,864
static constexpr long OUT2 = 75300864;   // max_timestamps (64,16,3,2)    = 6,144
static constexpr long OUT3 = 75307008;   // max_scores   (64,16,3)        = 3,072

// ---------------------------------------------------------------------------
// Kernel A: props_feats gather. One block per (b,s); 2000 float4 per block.
// ---------------------------------------------------------------------------
__global__ __launch_bounds__(256) void propfeat_kernel(
    const float* __restrict__ frames, const float* __restrict__ props,
    const float* __restrict__ duration, float* __restrict__ out) {
  int bs = blockIdx.x;            // 0..1023 = b*16+s
  int b = bs >> 4;
  float dur = duration[b];
  float p0 = props[bs * 2 + 0];
  float p1 = props[bs * 2 + 1];
  int s_fr = (int)(p0 / dur * 256.0f); if (s_fr > 255) s_fr = 255;
  int e_fr = (int)(p1 / dur * 256.0f); if (e_fr > 255) e_fr = 255;
  bool zp = (p0 == 0.0f) && (p1 == 0.0f) && (dur == 0.0f);
  float sf = (float)s_fr;
  float df = (float)(e_fr - s_fr);
  const float4* f4 = (const float4*)frames + (long)b * (256L * 125L);
  float4* o4 = (float4*)out + OUT0 / 4 + (long)bs * (16L * 125L);
  for (int k = threadIdx.x; k < 2000; k += 256) {
    int f = k / 125;            // frame step 0..15
    int w = k - f * 125;        // float4 within row
    float lin = sf + ((float)f * df) * (1.0f / 16.0f);   // exact: both integral
    int idx = (int)lin; if (idx > 255) idx = 255; if (idx < 0) idx = 0;
    float4 v = f4[(long)idx * 125 + w];
    if (zp) { v.x = 0.0f; v.y = 0.0f; v.z = 0.0f; v.w = 0.0f; }
    o4[k] = v;
  }
}

// ---------------------------------------------------------------------------
// Kernel B: fused overlaps write + top-3 (+sum) over scores.
// One block per (b,s), 512 threads (8 waves -> 4 blocks/CU = 100% occupancy).
// ---------------------------------------------------------------------------
__device__ __forceinline__ void insert3_full(float v, int id, float tv[3], int ti[3]) {
  // total order: larger value first; tie -> smaller index first (lax.top_k)
  if (v > tv[0] || (v == tv[0] && id < ti[0])) {
    tv[2] = tv[1]; ti[2] = ti[1];
    tv[1] = tv[0]; ti[1] = ti[0];
    tv[0] = v;     ti[0] = id;
  } else if (v > tv[1] || (v == tv[1] && id < ti[1])) {
    tv[2] = tv[1]; ti[2] = ti[1];
    tv[1] = v;     ti[1] = id;
  } else {
    tv[2] = v;     ti[2] = id;
  }
}

__device__ __forceinline__ void topk_insert(float v, int id, float tv[3], int ti[3]) {
  // fast-path guard: exact "would change state" condition
  if (v > tv[2] || (v == tv[2] && id < ti[2])) insert3_full(v, id, tv, ti);
}

__device__ __forceinline__ void process4(float4 sc, int k, float dur,
                                         float gs, float ge, bool gz,
                                         float4* __restrict__ o4,
                                         float tv[3], int ti[3], float& lsum) {
  const float inv256 = 1.0f / 256.0f;     // exact pow2 scaling
  int i = k >> 6;                         // row (start bin)
  int j = (k & 63) << 2;                  // col base (end bin)
  float ps  = (float)i * dur * inv256;    // (i*dur)/N, same rounding as ref
  float pmg = fmaxf(ps, gs);              // constant across the 4 elements
  float pmn = fminf(ps, gs);
  float4 ov;
  {
    float pe = (float)(j + 1) * dur * inv256;
    float in_ = fmaxf(0.0f, fminf(pe, ge) - pmg);
    float un  = fmaxf(0.0f, fmaxf(pe, ge) - pmn);
    ov.x = gz ? 0.0f : in_ * __builtin_amdgcn_rcpf(un + 1e-6f);
  }
  {
    float pe = (float)(j + 2) * dur * inv256;
    float in_ = fmaxf(0.0f, fminf(pe, ge) - pmg);
    float un  = fmaxf(0.0f, fmaxf(pe, ge) - pmn);
    ov.y = gz ? 0.0f : in_ * __builtin_amdgcn_rcpf(un + 1e-6f);
  }
  {
    float pe = (float)(j + 3) * dur * inv256;
    float in_ = fmaxf(0.0f, fminf(pe, ge) - pmg);
    float un  = fmaxf(0.0f, fmaxf(pe, ge) - pmn);
    ov.z = gz ? 0.0f : in_ * __builtin_amdgcn_rcpf(un + 1e-6f);
  }
  {
    float pe = (float)(j + 4) * dur * inv256;
    float in_ = fmaxf(0.0f, fminf(pe, ge) - pmg);
    float un  = fmaxf(0.0f, fmaxf(pe, ge) - pmn);
    ov.w = gz ? 0.0f : in_ * __builtin_amdgcn_rcpf(un + 1e-6f);
  }
  o4[k] = ov;

  int fidx = k << 2;
  topk_insert(sc.x, fidx + 0, tv, ti);
  topk_insert(sc.y, fidx + 1, tv, ti);
  topk_insert(sc.z, fidx + 2, tv, ti);
  topk_insert(sc.w, fidx + 3, tv, ti);
  lsum += sc.x + sc.y + sc.z + sc.w;
}

__global__ __launch_bounds__(512) void ov_topk_kernel(
    const float* __restrict__ scores, const float* __restrict__ yt,
    const float* __restrict__ duration, float* __restrict__ out) {
  __shared__ float sv[1536];
  __shared__ int   si[1536];
  __shared__ float ssum[512];

  int bs = blockIdx.x;      // b*16+s
  int b = bs >> 4;
  int tid = threadIdx.x;
  float dur = duration[b];
  float gs = yt[bs * 2 + 0];
  float ge = yt[bs * 2 + 1];
  bool gz = (gs == 0.0f) && (ge == 0.0f);
  const float inv256 = 1.0f / 256.0f;

  const float4* s4 = (const float4*)scores + (long)bs * 16384L;
  float4* o4 = (float4*)out + OUT1 / 4 + (long)bs * 16384L;

  float tv[3] = {-FLT_MAX, -FLT_MAX, -FLT_MAX};
  int   ti[3] = {0x7fffffff, 0x7fffffff, 0x7fffffff};
  float lsum = 0.0f;

  // 32 float4 per thread; process pairs so 2 loads are in flight per thread
  for (int it = 0; it < 32; it += 2) {
    int k0 = it * 512 + tid;
    int k1 = k0 + 512;
    float4 a = s4[k0];
    float4 c = s4[k1];
    process4(a, k0, dur, gs, ge, gz, o4, tv, ti, lsum);
    process4(c, k1, dur, gs, ge, gz, o4, tv, ti, lsum);
  }

  ssum[tid] = lsum;
  sv[tid * 3 + 0] = tv[0]; si[tid * 3 + 0] = ti[0];
  sv[tid * 3 + 1] = tv[1]; si[tid * 3 + 1] = ti[1];
  sv[tid * 3 + 2] = tv[2]; si[tid * 3 + 2] = ti[2];
  __syncthreads();

  // block sum reduce (only needs to clear the 0.001 threshold)
  for (int sft = 256; sft > 0; sft >>= 1) {
    if (tid < sft) ssum[tid] += ssum[tid + sft];
    __syncthreads();
  }

  // stage 1: 512 -> 64 candidate lists
  if (tid < 64) {
    float fv[3] = {-FLT_MAX, -FLT_MAX, -FLT_MAX};
    int   fi[3] = {0x7fffffff, 0x7fffffff, 0x7fffffff};
    for (int t = tid; t < 512; t += 64) {
      topk_insert(sv[t * 3 + 0], si[t * 3 + 0], fv, fi);
      topk_insert(sv[t * 3 + 1], si[t * 3 + 1], fv, fi);
      topk_insert(sv[t * 3 + 2], si[t * 3 + 2], fv, fi);
    }
    sv[tid * 3 + 0] = fv[0]; si[tid * 3 + 0] = fi[0];
    sv[tid * 3 + 1] = fv[1]; si[tid * 3 + 1] = fi[1];
    sv[tid * 3 + 2] = fv[2]; si[tid * 3 + 2] = fi[2];
  }
  __syncthreads();

  // stage 2: thread 0 merges 64 lists (192 candidates), writes outputs 2 & 3
  if (tid == 0) {
    float fv[3] = {-FLT_MAX, -FLT_MAX, -FLT_MAX};
    int   fi[3] = {0x7fffffff, 0x7fffffff, 0x7fffffff};
    for (int t = 0; t < 64; ++t) {
      topk_insert(sv[t * 3 + 0], si[t * 3 + 0], fv, fi);
      topk_insert(sv[t * 3 + 1], si[t * 3 + 1], fv, fi);
      topk_insert(sv[t * 3 + 2], si[t * 3 + 2], fv, fi);
    }
    float total = ssum[0];
    bool valid = total > 0.001f;
    float* o2 = out + OUT2 + (long)bs * 6;
    float* o3 = out + OUT3 + (long)bs * 3;
    for (int r = 0; r < 3; ++r) {
      float pi = (float)(fi[r] >> 8);     // top_idx // N
      float pj = (float)(fi[r] & 255);    // top_idx % N
      o3[r]         = valid ? fv[r] : 0.0f;
      o2[r * 2 + 0] = valid ? (pi * inv256) * dur : 0.0f;
      o2[r * 2 + 1] = valid ? (pj * inv256) * dur : 0.0f;
    }
  }
}

extern "C" void kernel_launch(void* const* d_in, const int* in_sizes, int n_in,
                              void* d_out, int out_size, void* d_ws, size_t ws_size,
                              hipStream_t stream) {
  const float* frames   = (const float*)d_in[0];  // (64,256,500)
  const float* props    = (const float*)d_in[1];  // (64,16,2)
  const float* duration = (const float*)d_in[2];  // (64,)
  const float* yt       = (const float*)d_in[3];  // (64,16,1,2)
  const float* scores   = (const float*)d_in[4];  // (64,16,1,256,256)
  float* out = (float*)d_out;

  hipLaunchKernelGGL(propfeat_kernel, dim3(1024), dim3(256), 0, stream,
                     frames, props, duration, out);
  hipLaunchKernelGGL(ov_topk_kernel, dim3(1024), dim3(512), 0, stream,
                     scores, yt, duration, out);
}

// Round 4
// 122.230 us; speedup vs baseline: 1.3766x; 1.2220x over previous
//
#include <hip/hip_runtime.h>
#include <float.h>

typedef float f32x4 __attribute__((ext_vector_type(4)));  // native vec for NT stores

// Problem constants (B=64, S=16, N=256, T=256, D=500, NUM_FRAMES=16, TOPK=3)
static constexpr long OUT0 = 0;          // props_feats  (1024, 16, 500)  = 8,192,000
static constexpr long OUT1 = 8192000;    // overlaps     (64,16,256,256)  = 67,108,864
static constexpr long OUT2 = 75300864;   // max_timestamps (64,16,3,2)    = 6,144
static constexpr long OUT3 = 75307008;   // max_scores   (64,16,3)        = 3,072

// ---------------------------------------------------------------------------
// Kernel A: props_feats gather. One block per (b,s); 2000 float4 per block.
// ---------------------------------------------------------------------------
__global__ __launch_bounds__(256) void propfeat_kernel(
    const float* __restrict__ frames, const float* __restrict__ props,
    const float* __restrict__ duration, float* __restrict__ out) {
  int bs = blockIdx.x;            // 0..1023 = b*16+s
  int b = bs >> 4;
  float dur = duration[b];
  float p0 = props[bs * 2 + 0];
  float p1 = props[bs * 2 + 1];
  int s_fr = (int)(p0 / dur * 256.0f); if (s_fr > 255) s_fr = 255;
  int e_fr = (int)(p1 / dur * 256.0f); if (e_fr > 255) e_fr = 255;
  bool zp = (p0 == 0.0f) && (p1 == 0.0f) && (dur == 0.0f);
  float sf = (float)s_fr;
  float df = (float)(e_fr - s_fr);
  const f32x4* f4 = (const f32x4*)frames + (long)b * (256L * 125L);
  f32x4* o4 = (f32x4*)out + OUT0 / 4 + (long)bs * (16L * 125L);
  for (int k = threadIdx.x; k < 2000; k += 256) {
    int f = k / 125;            // frame step 0..15
    int w = k - f * 125;        // float4 within row
    float lin = sf + ((float)f * df) * (1.0f / 16.0f);   // exact: both integral
    int idx = (int)lin; if (idx > 255) idx = 255; if (idx < 0) idx = 0;
    f32x4 v = f4[(long)idx * 125 + w];
    if (zp) v = (f32x4){0.0f, 0.0f, 0.0f, 0.0f};
    __builtin_nontemporal_store(v, &o4[k]);   // streaming out, never re-read
  }
}

// ---------------------------------------------------------------------------
// Kernel B: fused overlaps write + top-3 (+sum) over scores.
// One block per (b,s), 512 threads (8 waves x 4 blocks/CU = 100% occupancy).
// Column j = (k&63)<<2 depends only on tid -> pe and min/max(pe,ge) hoisted.
// ---------------------------------------------------------------------------

// Streaming-phase insert: ids strictly increase within a thread, so the
// lax.top_k tie-break (equal value -> smaller index) is automatic: the
// incumbent always has the smaller id. Plain > compares suffice.
__device__ __forceinline__ void insert_stream(float v, int id, float tv[3], int ti[3]) {
  if (v > tv[2]) {
    if (v > tv[0]) {
      tv[2] = tv[1]; ti[2] = ti[1];
      tv[1] = tv[0]; ti[1] = ti[0];
      tv[0] = v;     ti[0] = id;
    } else if (v > tv[1]) {
      tv[2] = tv[1]; ti[2] = ti[1];
      tv[1] = v;     ti[1] = id;
    } else {
      tv[2] = v;     ti[2] = id;
    }
  }
}

// Merge-phase insert: ids arrive out of order -> full tie-aware total order.
__device__ __forceinline__ void insert_merge(float v, int id, float tv[3], int ti[3]) {
  if (v > tv[2] || (v == tv[2] && id < ti[2])) {
    if (v > tv[0] || (v == tv[0] && id < ti[0])) {
      tv[2] = tv[1]; ti[2] = ti[1];
      tv[1] = tv[0]; ti[1] = ti[0];
      tv[0] = v;     ti[0] = id;
    } else if (v > tv[1] || (v == tv[1] && id < ti[1])) {
      tv[2] = tv[1]; ti[2] = ti[1];
      tv[1] = v;     ti[1] = id;
    } else {
      tv[2] = v;     ti[2] = id;
    }
  }
}

__global__ __launch_bounds__(512, 8) void ov_topk_kernel(
    const float* __restrict__ scores, const float* __restrict__ yt,
    const float* __restrict__ duration, float* __restrict__ out) {
  __shared__ float sv[1536];
  __shared__ int   si[1536];
  __shared__ float ssum[512];

  int bs = blockIdx.x;      // b*16+s
  int b = bs >> 4;
  int tid = threadIdx.x;
  float dur = duration[b];
  float gs = yt[bs * 2 + 0];
  float ge = yt[bs * 2 + 1];
  bool gz = (gs == 0.0f) && (ge == 0.0f);
  const float inv256 = 1.0f / 256.0f;   // exact pow2: x*inv256 == x/256

  // ---- per-thread loop invariants (column j fixed: k&63 == tid&63) ----
  int j = (tid & 63) << 2;
  float pe1 = (float)(j + 1) * dur * inv256;
  float pe2 = (float)(j + 2) * dur * inv256;
  float pe3 = (float)(j + 3) * dur * inv256;
  float pe4 = (float)(j + 4) * dur * inv256;
  float mn1 = fminf(pe1, ge), mx1 = fmaxf(pe1, ge);
  float mn2 = fminf(pe2, ge), mx2 = fmaxf(pe2, ge);
  float mn3 = fminf(pe3, ge), mx3 = fmaxf(pe3, ge);
  float mn4 = fminf(pe4, ge), mx4 = fmaxf(pe4, ge);

  const f32x4* s4 = (const f32x4*)scores + (long)bs * 16384L;
  f32x4* o4 = (f32x4*)out + OUT1 / 4 + (long)bs * 16384L;

  float tv[3] = {-FLT_MAX, -FLT_MAX, -FLT_MAX};
  int   ti[3] = {0x7fffffff, 0x7fffffff, 0x7fffffff};
  float lsum = 0.0f;

#define OVROW(K)                                                          \
  {                                                                       \
    int i = (K) >> 6;                                                     \
    float ps = (float)i * dur * inv256;                                   \
    float pmg = fmaxf(ps, gs);                                            \
    float pmn = fminf(ps, gs);                                            \
    f32x4 ov;                                                             \
    ov.x = gz ? 0.0f : fmaxf(0.0f, mn1 - pmg) *                           \
                       __builtin_amdgcn_rcpf(fmaxf(0.0f, mx1 - pmn) + 1e-6f); \
    ov.y = gz ? 0.0f : fmaxf(0.0f, mn2 - pmg) *                           \
                       __builtin_amdgcn_rcpf(fmaxf(0.0f, mx2 - pmn) + 1e-6f); \
    ov.z = gz ? 0.0f : fmaxf(0.0f, mn3 - pmg) *                           \
                       __builtin_amdgcn_rcpf(fmaxf(0.0f, mx3 - pmn) + 1e-6f); \
    ov.w = gz ? 0.0f : fmaxf(0.0f, mn4 - pmg) *                           \
                       __builtin_amdgcn_rcpf(fmaxf(0.0f, mx4 - pmn) + 1e-6f); \
    __builtin_nontemporal_store(ov, &o4[K]);                              \
  }

#define TOPK4(SC, K)                                                      \
  {                                                                       \
    int fidx = (K) << 2;                                                  \
    insert_stream(SC.x, fidx + 0, tv, ti);                                \
    insert_stream(SC.y, fidx + 1, tv, ti);                                \
    insert_stream(SC.z, fidx + 2, tv, ti);                                \
    insert_stream(SC.w, fidx + 3, tv, ti);                                \
    lsum += SC.x + SC.y + SC.z + SC.w;                                    \
  }

  // 32 float4/thread, 4 loads in flight per step
  for (int it = 0; it < 32; it += 4) {
    int k0 = it * 512 + tid;
    int k1 = k0 + 512;
    int k2 = k0 + 1024;
    int k3 = k0 + 1536;
    f32x4 a = s4[k0];
    f32x4 c = s4[k1];
    f32x4 d = s4[k2];
    f32x4 e = s4[k3];
    OVROW(k0); TOPK4(a, k0);
    OVROW(k1); TOPK4(c, k1);
    OVROW(k2); TOPK4(d, k2);
    OVROW(k3); TOPK4(e, k3);
  }
#undef OVROW
#undef TOPK4

  ssum[tid] = lsum;
  sv[tid * 3 + 0] = tv[0]; si[tid * 3 + 0] = ti[0];
  sv[tid * 3 + 1] = tv[1]; si[tid * 3 + 1] = ti[1];
  sv[tid * 3 + 2] = tv[2]; si[tid * 3 + 2] = ti[2];
  __syncthreads();

  // block sum reduce (only needs to clear the 0.001 threshold)
  for (int sft = 256; sft > 0; sft >>= 1) {
    if (tid < sft) ssum[tid] += ssum[tid + sft];
    __syncthreads();
  }

  // stage 1: 512 -> 64 candidate lists (tie-aware: ids out of order here)
  if (tid < 64) {
    float fv[3] = {-FLT_MAX, -FLT_MAX, -FLT_MAX};
    int   fi[3] = {0x7fffffff, 0x7fffffff, 0x7fffffff};
    for (int t = tid; t < 512; t += 64) {
      insert_merge(sv[t * 3 + 0], si[t * 3 + 0], fv, fi);
      insert_merge(sv[t * 3 + 1], si[t * 3 + 1], fv, fi);
      insert_merge(sv[t * 3 + 2], si[t * 3 + 2], fv, fi);
    }
    sv[tid * 3 + 0] = fv[0]; si[tid * 3 + 0] = fi[0];
    sv[tid * 3 + 1] = fv[1]; si[tid * 3 + 1] = fi[1];
    sv[tid * 3 + 2] = fv[2]; si[tid * 3 + 2] = fi[2];
  }
  __syncthreads();

  // stage 2: thread 0 merges 64 lists (192 candidates), writes outputs 2 & 3
  if (tid == 0) {
    float fv[3] = {-FLT_MAX, -FLT_MAX, -FLT_MAX};
    int   fi[3] = {0x7fffffff, 0x7fffffff, 0x7fffffff};
    for (int t = 0; t < 64; ++t) {
      insert_merge(sv[t * 3 + 0], si[t * 3 + 0], fv, fi);
      insert_merge(sv[t * 3 + 1], si[t * 3 + 1], fv, fi);
      insert_merge(sv[t * 3 + 2], si[t * 3 + 2], fv, fi);
    }
    float total = ssum[0];
    bool valid = total > 0.001f;
    float* o2 = out + OUT2 + (long)bs * 6;
    float* o3 = out + OUT3 + (long)bs * 3;
    for (int r = 0; r < 3; ++r) {
      float pi = (float)(fi[r] >> 8);     // top_idx // N
      float pj = (float)(fi[r] & 255);    // top_idx % N
      o3[r]         = valid ? fv[r] : 0.0f;
      o2[r * 2 + 0] = valid ? (pi * inv256) * dur : 0.0f;
      o2[r * 2 + 1] = valid ? (pj * inv256) * dur : 0.0f;
    }
  }
}

extern "C" void kernel_launch(void* const* d_in, const int* in_sizes, int n_in,
                              void* d_out, int out_size, void* d_ws, size_t ws_size,
                              hipStream_t stream) {
  const float* frames   = (const float*)d_in[0];  // (64,256,500)
  const float* props    = (const float*)d_in[1];  // (64,16,2)
  const float* duration = (const float*)d_in[2];  // (64,)
  const float* yt       = (const float*)d_in[3];  // (64,16,1,2)
  const float* scores   = (const float*)d_in[4];  // (64,16,1,256,256)
  float* out = (float*)d_out;

  hipLaunchKernelGGL(propfeat_kernel, dim3(1024), dim3(256), 0, stream,
                     frames, props, duration, out);
  hipLaunchKernelGGL(ov_topk_kernel, dim3(1024), dim3(512), 0, stream,
                     scores, yt, duration, out);
}